// Round 2
// baseline (329.245 us; speedup 1.0000x reference)
//
#include <hip/hip_runtime.h>
#include <hip/hip_bf16.h>
#include <stdint.h>

// Problem constants
#define BB 4
#define LL 4096
#define DD 1024
#define HH 16
#define WW 128
#define DH 64
#define NWIN 32            // LL / WW
#define MTOT (BB*LL)       // 16384
#define NQKV (3*DD)        // 3072

typedef short bf16x8 __attribute__((ext_vector_type(8)));
typedef float f32x4 __attribute__((ext_vector_type(4)));
typedef unsigned short u16;

__device__ __forceinline__ u16 f2bf(float f) {
    union { float f; uint32_t u; } v; v.f = f;
    uint32_t u = v.u;
    uint32_t r = (u + 0x7fffu + ((u >> 16) & 1u)) >> 16;
    return (u16)r;
}

// ---------------- fp32 -> bf16 conversion (vectorized) ----------------
__global__ __launch_bounds__(256) void cvt_f32_bf16(const float* __restrict__ in,
                                                    u16* __restrict__ out, int n8) {
    int i = blockIdx.x * blockDim.x + threadIdx.x;
    int stride = gridDim.x * blockDim.x;
    for (; i < n8; i += stride) {
        const float4* p = (const float4*)(in + (size_t)i * 8);
        float4 a = p[0], b = p[1];
        bf16x8 o;
        o[0] = (short)f2bf(a.x); o[1] = (short)f2bf(a.y);
        o[2] = (short)f2bf(a.z); o[3] = (short)f2bf(a.w);
        o[4] = (short)f2bf(b.x); o[5] = (short)f2bf(b.y);
        o[6] = (short)f2bf(b.z); o[7] = (short)f2bf(b.w);
        *(bf16x8*)(out + (size_t)i * 8) = o;
    }
}

// ---------------- shared MFMA GEMM core: 128x128 tile, BK=32, K=1024 ----------------
// A: [M x 1024] row-major bf16. Bw: [N x 1024] row-major bf16 (i.e. B^T form).
// 256 threads = 4 waves in 2x2; each wave owns a 64x64 sub-tile (4x4 fragments).
__device__ __forceinline__ void gemm_tile_1024(const u16* __restrict__ A,
                                               const u16* __restrict__ Bw,
                                               int row0, int col0,
                                               u16* Als, u16* Bls,
                                               f32x4 acc[4][4]) {
    const int tid  = threadIdx.x;
    const int lane = tid & 63;
    const int wave = tid >> 6;
    const int wr = (wave >> 1) * 64;
    const int wc = (wave & 1) * 64;
    const int colb = lane & 15;
    const int kgrp = lane >> 4;          // 0..3

    #pragma unroll
    for (int m = 0; m < 4; ++m)
        #pragma unroll
        for (int n = 0; n < 4; ++n)
            acc[m][n] = (f32x4){0.f, 0.f, 0.f, 0.f};

    // staging map: 512 chunks of 8 bf16 per matrix; thread does chunks tid, tid+256
    const int c0r = tid >> 2,        c0k = (tid & 3) * 8;
    const int c1r = (tid + 256) >> 2, c1k = ((tid + 256) & 3) * 8;

    for (int kt = 0; kt < 1024; kt += 32) {
        // prefetch to regs (global) before barrier
        bf16x8 ra0 = *(const bf16x8*)&A [(size_t)(row0 + c0r) * 1024 + kt + c0k];
        bf16x8 ra1 = *(const bf16x8*)&A [(size_t)(row0 + c1r) * 1024 + kt + c1k];
        bf16x8 rb0 = *(const bf16x8*)&Bw[(size_t)(col0 + c0r) * 1024 + kt + c0k];
        bf16x8 rb1 = *(const bf16x8*)&Bw[(size_t)(col0 + c1r) * 1024 + kt + c1k];
        __syncthreads();   // previous iteration's LDS reads complete
        *(bf16x8*)&Als[c0r * 32 + c0k] = ra0;
        *(bf16x8*)&Als[c1r * 32 + c1k] = ra1;
        *(bf16x8*)&Bls[c0r * 32 + c0k] = rb0;
        *(bf16x8*)&Bls[c1r * 32 + c1k] = rb1;
        __syncthreads();

        bf16x8 af[4], bf[4];
        #pragma unroll
        for (int m = 0; m < 4; ++m)
            af[m] = *(const bf16x8*)&Als[(wr + m * 16 + colb) * 32 + kgrp * 8];
        #pragma unroll
        for (int n = 0; n < 4; ++n)
            bf[n] = *(const bf16x8*)&Bls[(wc + n * 16 + colb) * 32 + kgrp * 8];
        #pragma unroll
        for (int m = 0; m < 4; ++m)
            #pragma unroll
            for (int n = 0; n < 4; ++n)
                acc[m][n] = __builtin_amdgcn_mfma_f32_16x16x32_bf16(af[m], bf[n], acc[m][n], 0, 0, 0);
    }
}

// ---------------- Kernel 1: QKV GEMM + bias + scatter to windowed q/k/vT ----------------
__global__ __launch_bounds__(256) void qkv_gemm_kernel(const u16* __restrict__ xb,
                                                       const u16* __restrict__ wb,
                                                       const float* __restrict__ bias,
                                                       u16* __restrict__ qd,
                                                       u16* __restrict__ kd,
                                                       u16* __restrict__ vtd) {
    __shared__ u16 Als[128 * 32];
    __shared__ u16 Bls[128 * 32];
    f32x4 acc[4][4];
    const int row0 = blockIdx.y * 128;
    const int col0 = blockIdx.x * 128;
    gemm_tile_1024(xb, wb, row0, col0, Als, Bls, acc);

    const int lane = threadIdx.x & 63;
    const int wave = threadIdx.x >> 6;
    const int wr = (wave >> 1) * 64;
    const int wc = (wave & 1) * 64;
    const int colb = lane & 15;
    const int rgrp = lane >> 4;

    #pragma unroll
    for (int m = 0; m < 4; ++m) {
        #pragma unroll
        for (int n = 0; n < 4; ++n) {
            #pragma unroll
            for (int j = 0; j < 4; ++j) {
                int gm = row0 + wr + m * 16 + rgrp * 4 + j;
                int gn = col0 + wc + n * 16 + colb;
                float v = acc[m][n][j] + bias[gn];
                int which = gn >> 10, c = gn & 1023, h = c >> 6, d = c & 63;
                int b = gm >> 12, l = gm & 4095, n0 = l >> 7, wq = l & 127;
                size_t wbase = (size_t)((b * HH + h) * NWIN + n0) * (WW * DH);
                if (which == 0)      qd [wbase + wq * 64 + d] = f2bf(v * 0.125f);
                else if (which == 1) kd [wbase + wq * 64 + d] = f2bf(v);
                else                 vtd[wbase + d * 128 + wq] = f2bf(v);
            }
        }
    }
}

// ---------------- Kernel 2: windowed causal attention ----------------
// One block per window (b,h,n0); 4 waves x 32 query rows each.
__global__ __launch_bounds__(256) void attn_kernel(const u16* __restrict__ q,
                                                   const u16* __restrict__ k,
                                                   const u16* __restrict__ vt,
                                                   u16* __restrict__ aout) {
    __shared__ u16 Ps[4][32 * 136];   // per-wave P tile, padded rows (272B stride)

    const int win = blockIdx.x;          // 0..2047
    const int b  = win >> 9;             // / (HH*NWIN)
    const int h  = (win >> 5) & 15;
    const int n0 = win & 31;
    const u16* qp = q  + (size_t)win * (WW * DH);
    const u16* kp = k  + (size_t)win * (WW * DH);
    const u16* vp = vt + (size_t)win * (WW * DH);

    const int lane = threadIdx.x & 63;
    const int wave = threadIdx.x >> 6;
    const int wrow = wave * 32;
    const int colb = lane & 15;
    const int kgrp = lane >> 4;
    const int rgrp = kgrp;               // same value: row-group for C/D layout

    // ---- S = Q K^T (q pre-scaled by 1/8) ----
    f32x4 s[2][8];
    #pragma unroll
    for (int m = 0; m < 2; ++m)
        #pragma unroll
        for (int n = 0; n < 8; ++n)
            s[m][n] = (f32x4){0.f, 0.f, 0.f, 0.f};

    #pragma unroll
    for (int kk = 0; kk < 2; ++kk) {
        bf16x8 aq[2];
        #pragma unroll
        for (int m = 0; m < 2; ++m)
            aq[m] = *(const bf16x8*)&qp[(wrow + m * 16 + colb) * 64 + kk * 32 + kgrp * 8];
        #pragma unroll
        for (int n = 0; n < 8; ++n) {
            bf16x8 bk = *(const bf16x8*)&kp[(n * 16 + colb) * 64 + kk * 32 + kgrp * 8];
            s[0][n] = __builtin_amdgcn_mfma_f32_16x16x32_bf16(aq[0], bk, s[0][n], 0, 0, 0);
            s[1][n] = __builtin_amdgcn_mfma_f32_16x16x32_bf16(aq[1], bk, s[1][n], 0, 0, 0);
        }
    }

    // ---- causal mask + row softmax (rows live across 16-lane groups) ----
    #pragma unroll
    for (int m = 0; m < 2; ++m) {
        #pragma unroll
        for (int j = 0; j < 4; ++j) {
            int row = wrow + m * 16 + rgrp * 4 + j;       // 0..127 in window
            float vals[8];
            float mx = -1e30f;
            #pragma unroll
            for (int n = 0; n < 8; ++n) {
                int col = n * 16 + colb;
                float v = s[m][n][j];
                if (col > row) v = -1e30f;
                vals[n] = v;
                mx = fmaxf(mx, v);
            }
            #pragma unroll
            for (int off = 1; off < 16; off <<= 1)
                mx = fmaxf(mx, __shfl_xor(mx, off, 64));
            float sum = 0.f;
            #pragma unroll
            for (int n = 0; n < 8; ++n) {
                float p = __expf(vals[n] - mx);
                vals[n] = p;
                sum += p;
            }
            #pragma unroll
            for (int off = 1; off < 16; off <<= 1)
                sum += __shfl_xor(sum, off, 64);
            float r = 1.0f / sum;
            #pragma unroll
            for (int n = 0; n < 8; ++n)
                Ps[wave][(m * 16 + rgrp * 4 + j) * 136 + n * 16 + colb] = f2bf(vals[n] * r);
        }
    }
    __syncthreads();

    // ---- O = P V  (B-operand = VT[d][k], B^T form) ----
    f32x4 o[2][4];
    #pragma unroll
    for (int m = 0; m < 2; ++m)
        #pragma unroll
        for (int n = 0; n < 4; ++n)
            o[m][n] = (f32x4){0.f, 0.f, 0.f, 0.f};

    #pragma unroll
    for (int kk = 0; kk < 4; ++kk) {
        bf16x8 ap[2];
        #pragma unroll
        for (int m = 0; m < 2; ++m)
            ap[m] = *(const bf16x8*)&Ps[wave][(m * 16 + colb) * 136 + kk * 32 + kgrp * 8];
        #pragma unroll
        for (int n = 0; n < 4; ++n) {
            bf16x8 bv = *(const bf16x8*)&vp[(n * 16 + colb) * 128 + kk * 32 + kgrp * 8];
            o[0][n] = __builtin_amdgcn_mfma_f32_16x16x32_bf16(ap[0], bv, o[0][n], 0, 0, 0);
            o[1][n] = __builtin_amdgcn_mfma_f32_16x16x32_bf16(ap[1], bv, o[1][n], 0, 0, 0);
        }
    }

    // ---- write attn output: [B*L][1024] bf16, d = h*64 + local ----
    #pragma unroll
    for (int m = 0; m < 2; ++m) {
        #pragma unroll
        for (int n = 0; n < 4; ++n) {
            #pragma unroll
            for (int j = 0; j < 4; ++j) {
                int row = wrow + m * 16 + rgrp * 4 + j;
                int l = n0 * 128 + row;
                int d = h * 64 + n * 16 + colb;
                aout[((size_t)(b * LL + l)) * DD + d] = f2bf(o[m][n][j]);
            }
        }
    }
}

// ---------------- Kernel 3: output projection GEMM + bias -> fp32 out ----------------
__global__ __launch_bounds__(256) void out_gemm_kernel(const u16* __restrict__ ab,
                                                       const u16* __restrict__ wb,
                                                       const float* __restrict__ bias,
                                                       float* __restrict__ out) {
    __shared__ u16 Als[128 * 32];
    __shared__ u16 Bls[128 * 32];
    f32x4 acc[4][4];
    const int row0 = blockIdx.y * 128;
    const int col0 = blockIdx.x * 128;
    gemm_tile_1024(ab, wb, row0, col0, Als, Bls, acc);

    const int lane = threadIdx.x & 63;
    const int wave = threadIdx.x >> 6;
    const int wr = (wave >> 1) * 64;
    const int wc = (wave & 1) * 64;
    const int colb = lane & 15;
    const int rgrp = lane >> 4;

    #pragma unroll
    for (int m = 0; m < 4; ++m) {
        #pragma unroll
        for (int n = 0; n < 4; ++n) {
            #pragma unroll
            for (int j = 0; j < 4; ++j) {
                int gm = row0 + wr + m * 16 + rgrp * 4 + j;
                int gn = col0 + wc + n * 16 + colb;
                out[(size_t)gm * DD + gn] = acc[m][n][j] + bias[gn];
            }
        }
    }
}

// ---------------- launch ----------------
extern "C" void kernel_launch(void* const* d_in, const int* in_sizes, int n_in,
                              void* d_out, int out_size, void* d_ws, size_t ws_size,
                              hipStream_t stream) {
    const float* x     = (const float*)d_in[0];
    const float* qkv_w = (const float*)d_in[1];
    const float* qkv_b = (const float*)d_in[2];
    const float* out_w = (const float*)d_in[3];
    const float* out_b = (const float*)d_in[4];
    float* out = (float*)d_out;

    char* ws = (char*)d_ws;
    // layout (bytes): x_bf16 (reused as attn_out) | qkv_w_bf16 | out_w_bf16 | q | k | vT
    u16* xb   = (u16*)(ws);                           // 16,777,216 elems
    u16* qwb  = (u16*)(ws + 33554432);                // 3,145,728 elems
    u16* owb  = (u16*)(ws + 39845888);                // 1,048,576 elems
    u16* qws  = (u16*)(ws + 41943040);                // 16,777,216 elems
    u16* kws  = (u16*)(ws + 75497472);
    u16* vtws = (u16*)(ws + 109051904);

    cvt_f32_bf16<<<2048, 256, 0, stream>>>(x, xb, 16777216 / 8);
    cvt_f32_bf16<<<1536, 256, 0, stream>>>(qkv_w, qwb, 3145728 / 8);
    cvt_f32_bf16<<<512, 256, 0, stream>>>(out_w, owb, 1048576 / 8);

    qkv_gemm_kernel<<<dim3(NQKV / 128, MTOT / 128), 256, 0, stream>>>(xb, qwb, qkv_b, qws, kws, vtws);

    attn_kernel<<<BB * HH * NWIN, 256, 0, stream>>>(qws, kws, vtws, xb /* attn_out */);

    out_gemm_kernel<<<dim3(DD / 128, MTOT / 128), 256, 0, stream>>>(xb, owb, out_b, out);
}

// Round 3
// 294.654 us; speedup vs baseline: 1.1174x; 1.1174x over previous
//
#include <hip/hip_runtime.h>
#include <hip/hip_bf16.h>
#include <stdint.h>

// Problem constants
#define BB 4
#define LL 4096
#define DD 1024
#define HH 16
#define WW 128
#define DH 64
#define NWIN 32            // LL / WW
#define MTOT (BB*LL)       // 16384
#define NQKV (3*DD)        // 3072

typedef short bf16x8 __attribute__((ext_vector_type(8)));
typedef float f32x4 __attribute__((ext_vector_type(4)));
typedef unsigned short u16;

__device__ __forceinline__ u16 f2bf(float f) {
    union { float f; uint32_t u; } v; v.f = f;
    uint32_t u = v.u;
    uint32_t r = (u + 0x7fffu + ((u >> 16) & 1u)) >> 16;
    return (u16)r;
}

// async global->LDS, 16 bytes per lane, HW dest = uniform base + lane*16
#define GLOAD_LDS16(gptr, ldsptr)                                                        \
    __builtin_amdgcn_global_load_lds((const __attribute__((address_space(1))) void*)(gptr), \
                                     (__attribute__((address_space(3))) void*)(ldsptr),      \
                                     16, 0, 0)

// ---------------- fp32 -> bf16 conversion (vectorized) ----------------
__global__ __launch_bounds__(256) void cvt_f32_bf16(const float* __restrict__ in,
                                                    u16* __restrict__ out, int n8) {
    int i = blockIdx.x * blockDim.x + threadIdx.x;
    int stride = gridDim.x * blockDim.x;
    for (; i < n8; i += stride) {
        const float4* p = (const float4*)(in + (size_t)i * 8);
        float4 a = p[0], b = p[1];
        bf16x8 o;
        o[0] = (short)f2bf(a.x); o[1] = (short)f2bf(a.y);
        o[2] = (short)f2bf(a.z); o[3] = (short)f2bf(a.w);
        o[4] = (short)f2bf(b.x); o[5] = (short)f2bf(b.y);
        o[6] = (short)f2bf(b.z); o[7] = (short)f2bf(b.w);
        *(bf16x8*)(out + (size_t)i * 8) = o;
    }
}

// ---------------- shared MFMA GEMM core: 128x128 tile, BK=32, K=1024 ----------------
// m97 structure: global_load_lds width-16 staging, 2-barrier K-loop.
// A: [M x 1024] row-major bf16. Bw: [N x 1024] row-major bf16 (B^T form).
// 256 threads = 4 waves in 2x2; each wave owns a 64x64 sub-tile (4x4 fragments).
__device__ __forceinline__ void gemm_tile_1024(const u16* __restrict__ A,
                                               const u16* __restrict__ Bw,
                                               int row0, int col0,
                                               u16* Als, u16* Bls,
                                               f32x4 acc[4][4]) {
    const int tid  = threadIdx.x;
    const int lane = tid & 63;
    const int wave = tid >> 6;
    const int wr = (wave >> 1) * 64;
    const int wc = (wave & 1) * 64;
    const int colb = lane & 15;
    const int kgrp = lane >> 4;          // 0..3

    #pragma unroll
    for (int m = 0; m < 4; ++m)
        #pragma unroll
        for (int n = 0; n < 4; ++n)
            acc[m][n] = (f32x4){0.f, 0.f, 0.f, 0.f};

    // staging: wave `w` fills LDS chunks 2w, 2w+1 of each tile (1 KiB each).
    // chunk c = rows [16c, 16c+16) of the [128][32] bf16 tile; lane l sources
    // global row 16c + (l>>2), col (l&3)*8 -> LDS offset c*1024 + l*16 (linear).
    const int c0 = wave * 2, c1 = wave * 2 + 1;
    const int lr = lane >> 2;            // row within chunk
    const int lk = (lane & 3) * 8;       // k-offset within row

    const u16* ga0 = &A [(size_t)(row0 + c0 * 16 + lr) * 1024 + lk];
    const u16* ga1 = &A [(size_t)(row0 + c1 * 16 + lr) * 1024 + lk];
    const u16* gb0 = &Bw[(size_t)(col0 + c0 * 16 + lr) * 1024 + lk];
    const u16* gb1 = &Bw[(size_t)(col0 + c1 * 16 + lr) * 1024 + lk];
    u16* la0 = &Als[c0 * 512];
    u16* la1 = &Als[c1 * 512];
    u16* lb0 = &Bls[c0 * 512];
    u16* lb1 = &Bls[c1 * 512];

    for (int kt = 0; kt < 1024; kt += 32) {
        __syncthreads();                 // prior iteration's LDS reads done
        GLOAD_LDS16(ga0 + kt, la0);
        GLOAD_LDS16(ga1 + kt, la1);
        GLOAD_LDS16(gb0 + kt, lb0);
        GLOAD_LDS16(gb1 + kt, lb1);
        __syncthreads();                 // compiler drains vmcnt before barrier

        bf16x8 af[4], bf[4];
        #pragma unroll
        for (int m = 0; m < 4; ++m)
            af[m] = *(const bf16x8*)&Als[(wr + m * 16 + colb) * 32 + kgrp * 8];
        #pragma unroll
        for (int n = 0; n < 4; ++n)
            bf[n] = *(const bf16x8*)&Bls[(wc + n * 16 + colb) * 32 + kgrp * 8];
        #pragma unroll
        for (int m = 0; m < 4; ++m)
            #pragma unroll
            for (int n = 0; n < 4; ++n)
                acc[m][n] = __builtin_amdgcn_mfma_f32_16x16x32_bf16(af[m], bf[n], acc[m][n], 0, 0, 0);
    }
}

// ---------------- Kernel 1: QKV GEMM + bias + scatter to windowed q/k/vT ----------------
__global__ __launch_bounds__(256) void qkv_gemm_kernel(const u16* __restrict__ xb,
                                                       const u16* __restrict__ wb,
                                                       const float* __restrict__ bias,
                                                       u16* __restrict__ qd,
                                                       u16* __restrict__ kd,
                                                       u16* __restrict__ vtd) {
    __shared__ u16 Als[128 * 32];
    __shared__ u16 Bls[128 * 32];
    f32x4 acc[4][4];
    const int row0 = blockIdx.y * 128;
    const int col0 = blockIdx.x * 128;
    gemm_tile_1024(xb, wb, row0, col0, Als, Bls, acc);

    const int lane = threadIdx.x & 63;
    const int wave = threadIdx.x >> 6;
    const int wr = (wave >> 1) * 64;
    const int wc = (wave & 1) * 64;
    const int colb = lane & 15;
    const int rgrp = lane >> 4;

    #pragma unroll
    for (int m = 0; m < 4; ++m) {
        #pragma unroll
        for (int n = 0; n < 4; ++n) {
            #pragma unroll
            for (int j = 0; j < 4; ++j) {
                int gm = row0 + wr + m * 16 + rgrp * 4 + j;
                int gn = col0 + wc + n * 16 + colb;
                float v = acc[m][n][j] + bias[gn];
                int which = gn >> 10, c = gn & 1023, h = c >> 6, d = c & 63;
                int b = gm >> 12, l = gm & 4095, n0 = l >> 7, wq = l & 127;
                size_t wbase = (size_t)((b * HH + h) * NWIN + n0) * (WW * DH);
                if (which == 0)      qd [wbase + wq * 64 + d] = f2bf(v * 0.125f);
                else if (which == 1) kd [wbase + wq * 64 + d] = f2bf(v);
                else                 vtd[wbase + d * 128 + wq] = f2bf(v);
            }
        }
    }
}

// ---------------- Kernel 2: windowed causal attention ----------------
// One block per window (b,h,n0); 4 waves x 32 query rows each.
__global__ __launch_bounds__(256) void attn_kernel(const u16* __restrict__ q,
                                                   const u16* __restrict__ k,
                                                   const u16* __restrict__ vt,
                                                   u16* __restrict__ aout) {
    __shared__ u16 Ps[4][32 * 136];   // per-wave P tile, padded rows (272B stride)

    const int win = blockIdx.x;          // 0..2047
    const int b  = win >> 9;             // / (HH*NWIN)
    const int h  = (win >> 5) & 15;
    const int n0 = win & 31;
    const u16* qp = q  + (size_t)win * (WW * DH);
    const u16* kp = k  + (size_t)win * (WW * DH);
    const u16* vp = vt + (size_t)win * (WW * DH);

    const int lane = threadIdx.x & 63;
    const int wave = threadIdx.x >> 6;
    const int wrow = wave * 32;
    const int colb = lane & 15;
    const int kgrp = lane >> 4;
    const int rgrp = kgrp;               // same value: row-group for C/D layout

    // ---- S = Q K^T (q pre-scaled by 1/8) ----
    f32x4 s[2][8];
    #pragma unroll
    for (int m = 0; m < 2; ++m)
        #pragma unroll
        for (int n = 0; n < 8; ++n)
            s[m][n] = (f32x4){0.f, 0.f, 0.f, 0.f};

    #pragma unroll
    for (int kk = 0; kk < 2; ++kk) {
        bf16x8 aq[2];
        #pragma unroll
        for (int m = 0; m < 2; ++m)
            aq[m] = *(const bf16x8*)&qp[(wrow + m * 16 + colb) * 64 + kk * 32 + kgrp * 8];
        #pragma unroll
        for (int n = 0; n < 8; ++n) {
            bf16x8 bk = *(const bf16x8*)&kp[(n * 16 + colb) * 64 + kk * 32 + kgrp * 8];
            s[0][n] = __builtin_amdgcn_mfma_f32_16x16x32_bf16(aq[0], bk, s[0][n], 0, 0, 0);
            s[1][n] = __builtin_amdgcn_mfma_f32_16x16x32_bf16(aq[1], bk, s[1][n], 0, 0, 0);
        }
    }

    // ---- causal mask + row softmax (rows live across 16-lane groups) ----
    #pragma unroll
    for (int m = 0; m < 2; ++m) {
        #pragma unroll
        for (int j = 0; j < 4; ++j) {
            int row = wrow + m * 16 + rgrp * 4 + j;       // 0..127 in window
            float vals[8];
            float mx = -1e30f;
            #pragma unroll
            for (int n = 0; n < 8; ++n) {
                int col = n * 16 + colb;
                float v = s[m][n][j];
                if (col > row) v = -1e30f;
                vals[n] = v;
                mx = fmaxf(mx, v);
            }
            #pragma unroll
            for (int off = 1; off < 16; off <<= 1)
                mx = fmaxf(mx, __shfl_xor(mx, off, 64));
            float sum = 0.f;
            #pragma unroll
            for (int n = 0; n < 8; ++n) {
                float p = __expf(vals[n] - mx);
                vals[n] = p;
                sum += p;
            }
            #pragma unroll
            for (int off = 1; off < 16; off <<= 1)
                sum += __shfl_xor(sum, off, 64);
            float r = 1.0f / sum;
            #pragma unroll
            for (int n = 0; n < 8; ++n)
                Ps[wave][(m * 16 + rgrp * 4 + j) * 136 + n * 16 + colb] = f2bf(vals[n] * r);
        }
    }
    __syncthreads();

    // ---- O = P V  (B-operand = VT[d][k], B^T form) ----
    f32x4 o[2][4];
    #pragma unroll
    for (int m = 0; m < 2; ++m)
        #pragma unroll
        for (int n = 0; n < 4; ++n)
            o[m][n] = (f32x4){0.f, 0.f, 0.f, 0.f};

    #pragma unroll
    for (int kk = 0; kk < 4; ++kk) {
        bf16x8 ap[2];
        #pragma unroll
        for (int m = 0; m < 2; ++m)
            ap[m] = *(const bf16x8*)&Ps[wave][(m * 16 + colb) * 136 + kk * 32 + kgrp * 8];
        #pragma unroll
        for (int n = 0; n < 4; ++n) {
            bf16x8 bv = *(const bf16x8*)&vp[(n * 16 + colb) * 128 + kk * 32 + kgrp * 8];
            o[0][n] = __builtin_amdgcn_mfma_f32_16x16x32_bf16(ap[0], bv, o[0][n], 0, 0, 0);
            o[1][n] = __builtin_amdgcn_mfma_f32_16x16x32_bf16(ap[1], bv, o[1][n], 0, 0, 0);
        }
    }

    // ---- write attn output: [B*L][1024] bf16, d = h*64 + local ----
    #pragma unroll
    for (int m = 0; m < 2; ++m) {
        #pragma unroll
        for (int n = 0; n < 4; ++n) {
            #pragma unroll
            for (int j = 0; j < 4; ++j) {
                int row = wrow + m * 16 + rgrp * 4 + j;
                int l = n0 * 128 + row;
                int d = h * 64 + n * 16 + colb;
                aout[((size_t)(b * LL + l)) * DD + d] = f2bf(o[m][n][j]);
            }
        }
    }
}

// ---------------- Kernel 3: output projection GEMM + bias -> fp32 out ----------------
__global__ __launch_bounds__(256) void out_gemm_kernel(const u16* __restrict__ ab,
                                                       const u16* __restrict__ wb,
                                                       const float* __restrict__ bias,
                                                       float* __restrict__ out) {
    __shared__ u16 Als[128 * 32];
    __shared__ u16 Bls[128 * 32];
    f32x4 acc[4][4];
    const int row0 = blockIdx.y * 128;
    const int col0 = blockIdx.x * 128;
    gemm_tile_1024(ab, wb, row0, col0, Als, Bls, acc);

    const int lane = threadIdx.x & 63;
    const int wave = threadIdx.x >> 6;
    const int wr = (wave >> 1) * 64;
    const int wc = (wave & 1) * 64;
    const int colb = lane & 15;
    const int rgrp = lane >> 4;

    #pragma unroll
    for (int m = 0; m < 4; ++m) {
        #pragma unroll
        for (int n = 0; n < 4; ++n) {
            #pragma unroll
            for (int j = 0; j < 4; ++j) {
                int gm = row0 + wr + m * 16 + rgrp * 4 + j;
                int gn = col0 + wc + n * 16 + colb;
                out[(size_t)gm * DD + gn] = acc[m][n][j] + bias[gn];
            }
        }
    }
}

// ---------------- launch ----------------
extern "C" void kernel_launch(void* const* d_in, const int* in_sizes, int n_in,
                              void* d_out, int out_size, void* d_ws, size_t ws_size,
                              hipStream_t stream) {
    const float* x     = (const float*)d_in[0];
    const float* qkv_w = (const float*)d_in[1];
    const float* qkv_b = (const float*)d_in[2];
    const float* out_w = (const float*)d_in[3];
    const float* out_b = (const float*)d_in[4];
    float* out = (float*)d_out;

    char* ws = (char*)d_ws;
    // layout (bytes): x_bf16 (reused as attn_out) | qkv_w_bf16 | out_w_bf16 | q | k | vT
    u16* xb   = (u16*)(ws);                           // 16,777,216 elems
    u16* qwb  = (u16*)(ws + 33554432);                // 3,145,728 elems
    u16* owb  = (u16*)(ws + 39845888);                // 1,048,576 elems
    u16* qws  = (u16*)(ws + 41943040);                // 16,777,216 elems
    u16* kws  = (u16*)(ws + 75497472);
    u16* vtws = (u16*)(ws + 109051904);

    cvt_f32_bf16<<<2048, 256, 0, stream>>>(x, xb, 16777216 / 8);
    cvt_f32_bf16<<<1536, 256, 0, stream>>>(qkv_w, qwb, 3145728 / 8);
    cvt_f32_bf16<<<512, 256, 0, stream>>>(out_w, owb, 1048576 / 8);

    qkv_gemm_kernel<<<dim3(NQKV / 128, MTOT / 128), 256, 0, stream>>>(xb, qwb, qkv_b, qws, kws, vtws);

    attn_kernel<<<BB * HH * NWIN, 256, 0, stream>>>(qws, kws, vtws, xb /* attn_out */);

    out_gemm_kernel<<<dim3(DD / 128, MTOT / 128), 256, 0, stream>>>(xb, owb, out_b, out);
}